// Round 7
// baseline (39377.890 us; speedup 1.0000x reference)
//
#include <hip/hip_runtime.h>
#include <cstdint>
#include <cstddef>

#define N_ 64
#define T_ 512
#define D_ 1024
#define H_ 1024
#define FH 4096  // 4*H

typedef __attribute__((ext_vector_type(8))) short bf16x8;
typedef __attribute__((ext_vector_type(4))) float f32x4;

static __device__ __forceinline__ uint16_t f2bf_(float f) {
  union { float f; uint32_t u; } v; v.f = f;
  uint32_t u = v.u + 0x7FFFu + ((v.u >> 16) & 1u);
  return (uint16_t)(u >> 16);
}
static __device__ __forceinline__ float bf2f_(uint16_t s) {
  union { uint32_t u; float f; } v; v.u = ((uint32_t)s) << 16;
  return v.f;
}

// ---------------------------------------------------------------------------
// Pack W [1024][4096] into MFMA B-fragment order, split bf16 hi/lo (round-5
// proven). col c = lane&15 -> (gate g=c>>2, jj=c&3) of block bid; k = kc*32 +
// (lane>>4)*8 + e. dst[((bid*32 + kc)*64 + lane)*8 + e]. 2048 x 256 grid.
// ---------------------------------------------------------------------------
__global__ __launch_bounds__(256) void pack_w_k(const float* __restrict__ W,
                                                ushort* __restrict__ hi,
                                                ushort* __restrict__ lo) {
  const int i = blockIdx.x * 256 + threadIdx.x;  // 524288 = 256*32*64
  const int lane = i & 63, kc = (i >> 6) & 31, bid = i >> 11;
  const int c = lane & 15;
  const int col = (c >> 2) * H_ + (bid << 2) + (c & 3);
  const int k0 = (kc << 5) + ((lane >> 4) << 3);
  const size_t o = ((size_t)(bid * 32 + kc) * 64 + lane) * 8;
#pragma unroll
  for (int e = 0; e < 8; ++e) {
    float v = W[(size_t)(k0 + e) * FH + col];
    ushort h = f2bf_(v);
    hi[o + e] = h;
    lo[o + e] = f2bf_(v - bf2f_(h));
  }
}

// ---------------------------------------------------------------------------
// Elementwise f32 -> bf16 hi/lo split (row-major preserved). One float4 per
// thread. Optionally zeroes the grid-barrier counter (any one invocation).
// ---------------------------------------------------------------------------
__global__ __launch_bounds__(256) void split_f32_k(const float* __restrict__ src,
                                                   ushort* __restrict__ hi,
                                                   ushort* __restrict__ lo,
                                                   unsigned* bar) {
  if (bar != nullptr && blockIdx.x == 0 && threadIdx.x == 0) *bar = 0u;
  const size_t i = (size_t)blockIdx.x * 256 + threadIdx.x;
  float4 v = reinterpret_cast<const float4*>(src)[i];
  ushort4 h, l;
  h.x = f2bf_(v.x); l.x = f2bf_(v.x - bf2f_(h.x));
  h.y = f2bf_(v.y); l.y = f2bf_(v.y - bf2f_(h.y));
  h.z = f2bf_(v.z); l.z = f2bf_(v.z - bf2f_(h.z));
  h.w = f2bf_(v.w); l.w = f2bf_(v.w - bf2f_(h.w));
  reinterpret_cast<ushort4*>(hi)[i] = h;
  reinterpret_cast<ushort4*>(lo)[i] = l;
}

// ---------------------------------------------------------------------------
// Persistent fused LSTM scan. 256 blocks x 512 thr (8 waves), plain launch.
// Block bid owns 4 h-cols (16 gate cols). Waves: mt = w&3 (16-row M tile),
// kh = w>>2: kh=0 -> h@Wh, kh=1 -> x_t@Wx (pre-split bf16). Split-bf16 MFMA:
// D = Ah*Bh + Ah*Bl + Al*Bh, two independent acc chains over kc halves.
// B fragments read DIRECTLY from global (lane-linear packed layout, L2-warm).
// Epilogue (threads 0..255) holds c in VGPR, writes out + next-h ping-pong
// (bf16 hi/lo). Steps separated by a software grid barrier (monotonic counter,
// agent-scope release/acquire). Co-residency by construction: LDS 8.7KB,
// <=128 VGPR (__launch_bounds__(512,4)) -> >=2 blocks/CU capacity, 256 blocks
// on 256 CUs.
// ---------------------------------------------------------------------------
__global__ __launch_bounds__(512, 4) void lstm_persist_mfma(
    const ushort* __restrict__ Whh, const ushort* __restrict__ Whl,
    const ushort* __restrict__ Wxh, const ushort* __restrict__ Wxl,
    const ushort* __restrict__ xh, const ushort* __restrict__ xl,
    const float* __restrict__ bias,
    ushort* __restrict__ hb0h, ushort* __restrict__ hb0l,
    ushort* __restrict__ hb1h, ushort* __restrict__ hb1l,
    float* __restrict__ out, unsigned* __restrict__ bar) {
  __shared__ float pre[128 * 17];

  const int tid = threadIdx.x, bid = blockIdx.x;
  const int lane = tid & 63, w = tid >> 6;
  const int mt = w & 3, kh = w >> 2;
  const int arow = (mt << 4) | (lane & 15);
  const int kg = lane >> 4;
  const int dc = lane & 15, dr = (lane >> 4) << 2;
  const int en = tid >> 2, ejj = tid & 3;

  float bias4[4] = {0.f, 0.f, 0.f, 0.f};
  float creg = 0.f;
  if (tid < 256) {
#pragma unroll
    for (int g = 0; g < 4; ++g) bias4[g] = bias[g * H_ + (bid << 2) + ejj];
  }

  // B fragment bases (bf16x8 units); stride per kc = 64 units
  const bf16x8* Bh = reinterpret_cast<const bf16x8*>(kh ? Wxh : Whh) +
                     (size_t)bid * 2048 + lane;
  const bf16x8* Bl = reinterpret_cast<const bf16x8*>(kh ? Wxl : Whl) +
                     (size_t)bid * 2048 + lane;

  const ushort* rdh[2] = {hb0h, hb1h};
  const ushort* rdl[2] = {hb0l, hb1l};
  ushort* wrh[2] = {hb0h, hb1h};
  ushort* wrl[2] = {hb0l, hb1l};

  for (int t = 0; t < T_; ++t) {
    const ushort *Ah, *Al;
    if (kh == 0) {
      Ah = rdh[t & 1] + arow * 1024 + (kg << 3);
      Al = rdl[t & 1] + arow * 1024 + (kg << 3);
    } else {
      const size_t ro = ((size_t)arow * T_ + t) * D_ + (kg << 3);
      Ah = xh + ro;
      Al = xl + ro;
    }

    f32x4 acc0 = {0.f, 0.f, 0.f, 0.f};
    f32x4 acc1 = {0.f, 0.f, 0.f, 0.f};
#pragma unroll 4
    for (int kc = 0; kc < 16; ++kc) {
      bf16x8 a0h = *reinterpret_cast<const bf16x8*>(Ah + (kc << 5));
      bf16x8 a0l = *reinterpret_cast<const bf16x8*>(Al + (kc << 5));
      bf16x8 a1h = *reinterpret_cast<const bf16x8*>(Ah + ((kc + 16) << 5));
      bf16x8 a1l = *reinterpret_cast<const bf16x8*>(Al + ((kc + 16) << 5));
      bf16x8 b0h = Bh[kc << 6];
      bf16x8 b0l = Bl[kc << 6];
      bf16x8 b1h = Bh[(kc + 16) << 6];
      bf16x8 b1l = Bl[(kc + 16) << 6];
      acc0 = __builtin_amdgcn_mfma_f32_16x16x32_bf16(a0h, b0h, acc0, 0, 0, 0);
      acc1 = __builtin_amdgcn_mfma_f32_16x16x32_bf16(a1h, b1h, acc1, 0, 0, 0);
      acc0 = __builtin_amdgcn_mfma_f32_16x16x32_bf16(a0h, b0l, acc0, 0, 0, 0);
      acc1 = __builtin_amdgcn_mfma_f32_16x16x32_bf16(a1h, b1l, acc1, 0, 0, 0);
      acc0 = __builtin_amdgcn_mfma_f32_16x16x32_bf16(a0l, b0h, acc0, 0, 0, 0);
      acc1 = __builtin_amdgcn_mfma_f32_16x16x32_bf16(a1l, b1h, acc1, 0, 0, 0);
    }
    f32x4 accs = acc0 + acc1;

    // D layout (m89-verified): col = lane&15, row = (lane>>4)*4 + r
#pragma unroll
    for (int r = 0; r < 4; ++r)
      pre[((kh << 6) + (mt << 4) + dr + r) * 17 + dc] = accs[r];
    __syncthreads();

    if (tid < 256) {
      float a[4];
#pragma unroll
      for (int g = 0; g < 4; ++g)
        a[g] = pre[en * 17 + (g << 2) + ejj] +
               pre[(64 + en) * 17 + (g << 2) + ejj] + bias4[g];
      float iv = 1.f / (1.f + __expf(-a[0]));
      float fv = 1.f / (1.f + __expf(-a[1]));
      float ov = 1.f / (1.f + __expf(-a[2]));
      float gv = tanhf(a[3]);
      creg = fmaf(fv, creg, iv * gv);
      float hn = ov * tanhf(creg);
      out[(size_t)en * ((size_t)T_ * H_) + (size_t)t * H_ + (bid << 2) + ejj] = hn;
      const int o = (t + 1) & 1;
      const int hx = en * H_ + (bid << 2) + ejj;
      ushort hh = f2bf_(hn);
      wrh[o][hx] = hh;
      wrl[o][hx] = f2bf_(hn - bf2f_(hh));
    }

    // ---- grid barrier (release h writes -> all blocks -> acquire) ----
    __threadfence();
    __syncthreads();
    if (tid == 0) {
      __hip_atomic_fetch_add(bar, 1u, __ATOMIC_RELEASE, __HIP_MEMORY_SCOPE_AGENT);
      const unsigned tgt = 256u * (unsigned)(t + 1);
      while (__hip_atomic_load(bar, __ATOMIC_ACQUIRE, __HIP_MEMORY_SCOPE_AGENT) < tgt)
        __builtin_amdgcn_s_sleep(1);
    }
    __syncthreads();
  }
}

// ---------------------------------------------------------------------------
// Fallback (tiny ws): fused per-step VALU kernel (round-1 proven). Slow.
// ---------------------------------------------------------------------------
__global__ __launch_bounds__(256) void lstm_step_fb(
    const float* __restrict__ xt, const float* __restrict__ Wx,
    const float* __restrict__ Wh, const float* __restrict__ bias,
    const float* __restrict__ h_prev, long long hstride,
    float* __restrict__ cbuf, float* __restrict__ h_out, int first) {
  __shared__ float hS[32][128];
  __shared__ float wT[32][132];
  __shared__ float pre[32][34];
  const int tid = threadIdx.x;
  const int colblk = blockIdx.x & 127;
  const int nh = blockIdx.x >> 7;
  const int j0 = colblk << 3;
  const int n0 = nh << 5;
  const int ng = tid >> 4, cg2 = tid & 15;
  const int na = ng << 1, ca = cg2 << 1;

  float acc[2][2] = {{0.f, 0.f}, {0.f, 0.f}};

#pragma unroll
  for (int pr = 0; pr < 2; ++pr) {
    const float* src = (pr == 0) ? h_prev : xt;
    long long sstr = (pr == 0) ? hstride : (long long)T_ * D_;
    const float* W = (pr == 0) ? Wh : Wx;
    for (int k0 = 0; k0 < 1024; k0 += 128) {
      __syncthreads();
#pragma unroll
      for (int p = 0; p < 4; ++p) {
        int idx = tid + (p << 8);
        int r = idx >> 5, c4 = (idx & 31) << 2;
        *reinterpret_cast<float4*>(&hS[r][c4]) =
            *reinterpret_cast<const float4*>(src + (size_t)(n0 + r) * sstr + k0 + c4);
      }
#pragma unroll
      for (int p = 0; p < 4; ++p) {
        int idx = tid + (p << 8);
        int k = idx >> 3, sub = idx & 7;
        int g = sub >> 1, hf = (sub & 1) << 2;
        float4 v = *reinterpret_cast<const float4*>(
            W + (size_t)(k0 + k) * FH + g * H_ + j0 + hf);
        int cb = (g << 3) + hf;
        wT[cb][k] = v.x; wT[cb + 1][k] = v.y; wT[cb + 2][k] = v.z; wT[cb + 3][k] = v.w;
      }
      __syncthreads();
#pragma unroll
      for (int kk = 0; kk < 128; kk += 4) {
        float4 h0v = *reinterpret_cast<const float4*>(&hS[na][kk]);
        float4 h1v = *reinterpret_cast<const float4*>(&hS[na + 1][kk]);
        float4 w0 = *reinterpret_cast<const float4*>(&wT[ca][kk]);
        float4 w1 = *reinterpret_cast<const float4*>(&wT[ca + 1][kk]);
        acc[0][0] = fmaf(h0v.x, w0.x, acc[0][0]); acc[0][0] = fmaf(h0v.y, w0.y, acc[0][0]);
        acc[0][0] = fmaf(h0v.z, w0.z, acc[0][0]); acc[0][0] = fmaf(h0v.w, w0.w, acc[0][0]);
        acc[0][1] = fmaf(h0v.x, w1.x, acc[0][1]); acc[0][1] = fmaf(h0v.y, w1.y, acc[0][1]);
        acc[0][1] = fmaf(h0v.z, w1.z, acc[0][1]); acc[0][1] = fmaf(h0v.w, w1.w, acc[0][1]);
        acc[1][0] = fmaf(h1v.x, w0.x, acc[1][0]); acc[1][0] = fmaf(h1v.y, w0.y, acc[1][0]);
        acc[1][0] = fmaf(h1v.z, w0.z, acc[1][0]); acc[1][0] = fmaf(h1v.w, w0.w, acc[1][0]);
        acc[1][1] = fmaf(h1v.x, w1.x, acc[1][1]); acc[1][1] = fmaf(h1v.y, w1.y, acc[1][1]);
        acc[1][1] = fmaf(h1v.z, w1.z, acc[1][1]); acc[1][1] = fmaf(h1v.w, w1.w, acc[1][1]);
      }
    }
  }

  pre[na][ca] = acc[0][0];
  pre[na][ca + 1] = acc[0][1];
  pre[na + 1][ca] = acc[1][0];
  pre[na + 1][ca + 1] = acc[1][1];
  __syncthreads();

  const int nl = tid >> 3, jl = tid & 7;
  const int n = n0 + nl;
  const int jg = j0 + jl;
  float ai = pre[nl][jl] + bias[jg];
  float af = pre[nl][8 + jl] + bias[H_ + jg];
  float ao = pre[nl][16 + jl] + bias[2 * H_ + jg];
  float ag = pre[nl][24 + jl] + bias[3 * H_ + jg];
  float cp = first ? 0.0f : cbuf[n * H_ + jg];
  float iv = 1.f / (1.f + __expf(-ai));
  float fv = 1.f / (1.f + __expf(-af));
  float ov = 1.f / (1.f + __expf(-ao));
  float gv = tanhf(ag);
  float cn = fmaf(fv, cp, iv * gv);
  cbuf[n * H_ + jg] = cn;
  h_out[(size_t)n * ((size_t)T_ * H_) + jg] = ov * tanhf(cn);
}

// ---------------------------------------------------------------------------
extern "C" void kernel_launch(void* const* d_in, const int* in_sizes, int n_in,
                              void* d_out, int out_size, void* d_ws, size_t ws_size,
                              hipStream_t stream) {
  (void)in_sizes; (void)n_in; (void)out_size;
  const float* x  = (const float*)d_in[0];
  const float* h0 = (const float*)d_in[1];
  const float* Wx = (const float*)d_in[2];
  const float* Wh = (const float*)d_in[3];
  const float* b  = (const float*)d_in[4];
  float* out = (float*)d_out;

  const size_t MB = 1u << 20;
  char* p = (char*)d_ws;

  if (ws_size >= 163 * MB) {
    unsigned* bar = (unsigned*)p;
    ushort* Whh = (ushort*)(p + 1 * MB);
    ushort* Whl = (ushort*)(p + 9 * MB);
    ushort* Wxh = (ushort*)(p + 17 * MB);
    ushort* Wxl = (ushort*)(p + 25 * MB);
    ushort* hb0h = (ushort*)(p + 33 * MB);
    ushort* hb0l = hb0h + 65536;
    ushort* hb1h = hb0l + 65536;
    ushort* hb1l = hb1h + 65536;
    ushort* xh = (ushort*)(p + 34 * MB);   // 64 MB
    ushort* xl = (ushort*)(p + 98 * MB);   // 64 MB

    pack_w_k<<<dim3(2048), dim3(256), 0, stream>>>(Wh, Whh, Whl);
    pack_w_k<<<dim3(2048), dim3(256), 0, stream>>>(Wx, Wxh, Wxl);
    // x: 64*512*1024 floats = 8,388,608 float4 -> 32768 blocks (also zeroes bar)
    split_f32_k<<<dim3(32768), dim3(256), 0, stream>>>(x, xh, xl, bar);
    // h0: 64*1024 floats = 16384 float4 -> 64 blocks
    split_f32_k<<<dim3(64), dim3(256), 0, stream>>>(h0, hb0h, hb0l, nullptr);

    lstm_persist_mfma<<<dim3(256), dim3(512), 0, stream>>>(
        Whh, Whl, Wxh, Wxl, xh, xl, b, hb0h, hb0l, hb1h, hb1l, out, bar);
  } else {
    float* cbuf = (float*)p;  // 256 KB
    for (int t = 0; t < T_; ++t) {
      const float* hp = (t == 0) ? h0 : out + (size_t)(t - 1) * H_;
      long long hstr = (t == 0) ? (long long)H_ : (long long)T_ * H_;
      lstm_step_fb<<<dim3(256), dim3(256), 0, stream>>>(
          x + (size_t)t * D_, Wx, Wh, b, hp, hstr, cbuf,
          out + (size_t)t * H_, t == 0);
    }
  }
}